// Round 9
// baseline (287.096 us; speedup 1.0000x reference)
//
#include <hip/hip_runtime.h>

#define D 128

typedef __attribute__((ext_vector_type(8))) short bf16x8;   // 8 bf16 in 4 VGPRs
typedef __attribute__((ext_vector_type(4))) float f32x4;

__device__ __forceinline__ unsigned short f2bf(float x) {
    unsigned int u = __float_as_uint(x);
    u += 0x7fffu + ((u >> 16) & 1u);   // round-to-nearest-even
    return (unsigned short)(u >> 16);
}
__device__ __forceinline__ unsigned int pk2(float lo, float hi) {
    return ((unsigned int)f2bf(hi) << 16) | (unsigned int)f2bf(lo);
}
__device__ __forceinline__ float bf_lo(unsigned int u) { return __uint_as_float(u << 16); }
__device__ __forceinline__ float bf_hi(unsigned int u) { return __uint_as_float(u & 0xffff0000u); }

// ============================ prep: zero degrees + fp32->bf16 ==============
// Both parts are pure streaming writes; hist launches after, so no hazard.
__global__ __launch_bounds__(256) void prep0(const float4* __restrict__ f,
                                             uint4* __restrict__ o, int n8,
                                             int* __restrict__ c, int nzero) {
    int i = blockIdx.x * 256 + threadIdx.x;
    if (i < n8) {
        float4 a = f[2 * i];
        float4 b = f[2 * i + 1];
        o[i] = make_uint4(pk2(a.x, a.y), pk2(a.z, a.w), pk2(b.x, b.y), pk2(b.z, b.w));
    }
    if (i < nzero) c[i] = 0;
}

// ============================ histogram, 4 atomics in flight per thread ====
// R8's prep issued ONE atomic per thread (wave retires after 1 atomic inst ->
// atomic MLP/wave = 1, 21 G atomics/s, VALUBusy 1.5%). Grid-stride x4: load 4
// independent dsts (coalesced), then 4 independent atomics in flight.
__global__ __launch_bounds__(256) void hist4(const int* __restrict__ dc,
                                             const int* __restrict__ de,
                                             int* __restrict__ c, int E, int N) {
    const int nt   = gridDim.x * 256;
    const int twoE = 2 * E;
    const int i0 = blockIdx.x * 256 + threadIdx.x;
    const int i1 = i0 + nt, i2 = i0 + 2 * nt, i3 = i0 + 3 * nt;
    int d0 = -1, d1 = -1, d2 = -1, d3 = -1;
    if (i0 < twoE) d0 = (i0 < E) ? dc[i0] : de[i0 - E] + N;
    if (i1 < twoE) d1 = (i1 < E) ? dc[i1] : de[i1 - E] + N;
    if (i2 < twoE) d2 = (i2 < E) ? dc[i2] : de[i2 - E] + N;
    if (i3 < twoE) d3 = (i3 < E) ? dc[i3] : de[i3 - E] + N;
    if (d0 >= 0) atomicAdd(&c[d0], 1);
    if (d1 >= 0) atomicAdd(&c[d1], 1);
    if (d2 >= 0) atomicAdd(&c[d2], 1);
    if (d3 >= 0) atomicAdd(&c[d3], 1);
}

// per-block exclusive scan of c -> row_ptr, block totals -> aux
__global__ __launch_bounds__(256) void scan_block(const int* __restrict__ c,
                                                  int* __restrict__ row_ptr,
                                                  int* __restrict__ aux, int n) {
    __shared__ int sd[256];
    const int t = threadIdx.x;
    const int i = blockIdx.x * 256 + t;
    int x = (i < n) ? c[i] : 0;
    sd[t] = x;
    __syncthreads();
#pragma unroll
    for (int off = 1; off < 256; off <<= 1) {
        int y = (t >= off) ? sd[t - off] : 0;
        __syncthreads();
        sd[t] += y;
        __syncthreads();
    }
    if (i < n) row_ptr[i] = sd[t] - x;  // exclusive
    if (t == 255) aux[blockIdx.x] = sd[255];
}

// row_ptr[i] += sum(aux[0..blockIdx)) computed in-block (aux <= 512 entries);
// also seeds cursor = row_ptr (absolute CSR indices for fill) and row_ptr[n].
__global__ __launch_bounds__(256) void scan_add(int* __restrict__ row_ptr,
                                                const int* __restrict__ aux,
                                                const int* __restrict__ c,
                                                int* __restrict__ cursor, int n) {
    __shared__ int red[256];
    const int t = threadIdx.x;
    const int b = blockIdx.x;
    int acc = 0;
    for (int j = t; j < b; j += 256) acc += aux[j];
    red[t] = acc;
    __syncthreads();
#pragma unroll
    for (int off = 128; off > 0; off >>= 1) {
        if (t < off) red[t] += red[t + off];
        __syncthreads();
    }
    const int base = red[0];
    int i = b * 256 + t;
    if (i < n) {
        int r = row_ptr[i] + base;
        row_ptr[i] = r;
        cursor[i]  = r;
        if (i == n - 1) row_ptr[n] = r + c[i];
    }
}

// ============================ CSR fill, 4 in flight per thread =============
__global__ __launch_bounds__(256) void fill4(const int* __restrict__ sc,
                                             const int* __restrict__ dc,
                                             const int* __restrict__ se,
                                             const int* __restrict__ de,
                                             int* __restrict__ cursor,
                                             unsigned short* __restrict__ csr,
                                             int E, int N) {
    const int nt   = gridDim.x * 256;
    const int twoE = 2 * E;
    const int i0 = blockIdx.x * 256 + threadIdx.x;
    const int i1 = i0 + nt, i2 = i0 + 2 * nt, i3 = i0 + 3 * nt;
    int d0 = -1, d1 = -1, d2 = -1, d3 = -1;
    int s0 = 0, s1 = 0, s2 = 0, s3 = 0;
    if (i0 < twoE) { if (i0 < E) { d0 = dc[i0]; s0 = sc[i0]; } else { d0 = de[i0-E] + N; s0 = se[i0-E]; } }
    if (i1 < twoE) { if (i1 < E) { d1 = dc[i1]; s1 = sc[i1]; } else { d1 = de[i1-E] + N; s1 = se[i1-E]; } }
    if (i2 < twoE) { if (i2 < E) { d2 = dc[i2]; s2 = sc[i2]; } else { d2 = de[i2-E] + N; s2 = se[i2-E]; } }
    if (i3 < twoE) { if (i3 < E) { d3 = dc[i3]; s3 = sc[i3]; } else { d3 = de[i3-E] + N; s3 = se[i3-E]; } }
    int x0 = 0, x1 = 0, x2 = 0, x3 = 0;
    if (d0 >= 0) x0 = atomicAdd(&cursor[d0], 1);
    if (d1 >= 0) x1 = atomicAdd(&cursor[d1], 1);
    if (d2 >= 0) x2 = atomicAdd(&cursor[d2], 1);
    if (d3 >= 0) x3 = atomicAdd(&cursor[d3], 1);
    if (d0 >= 0) csr[x0] = (unsigned short)s0;
    if (d1 >= 0) csr[x1] = (unsigned short)s1;
    if (d2 >= 0) csr[x2] = (unsigned short)s2;
    if (d3 >= 0) csr[x3] = (unsigned short)s3;
}

// ============================ aggregate (unchanged from R8) ================
// 2 rows per wave: 32 lanes x 8B per row; unroll x4 -> 8 outstanding loads.
__global__ __launch_bounds__(1024) void aggregate_bf(const unsigned short* __restrict__ fbf,
                                                     const unsigned short* __restrict__ csr,
                                                     const int* __restrict__ row_ptr,
                                                     unsigned short* __restrict__ S, int N2) {
    const int v   = blockIdx.x * 32 + ((threadIdx.x >> 6) << 1) + ((threadIdx.x >> 5) & 1);
    const int l32 = threadIdx.x & 31;
    if (v < N2) {
        const int beg = row_ptr[v];
        const int end = row_ptr[v + 1];
        const int off = l32 * 4;
        float4 s0 = make_float4(0.f, 0.f, 0.f, 0.f);
        float4 s1 = make_float4(0.f, 0.f, 0.f, 0.f);
        float4 s2 = make_float4(0.f, 0.f, 0.f, 0.f);
        float4 s3 = make_float4(0.f, 0.f, 0.f, 0.f);
#define ACCUM(U, SA)                  \
        SA.x += bf_lo(U.x);           \
        SA.y += bf_hi(U.x);           \
        SA.z += bf_lo(U.y);           \
        SA.w += bf_hi(U.y);
        int e = beg;
        for (; e + 4 <= end; e += 4) {
            int i0 = csr[e + 0];
            int i1 = csr[e + 1];
            int i2 = csr[e + 2];
            int i3 = csr[e + 3];
            uint2 u0 = *(const uint2*)(fbf + (size_t)i0 * D + off);
            uint2 u1 = *(const uint2*)(fbf + (size_t)i1 * D + off);
            uint2 u2 = *(const uint2*)(fbf + (size_t)i2 * D + off);
            uint2 u3 = *(const uint2*)(fbf + (size_t)i3 * D + off);
            ACCUM(u0, s0) ACCUM(u1, s1) ACCUM(u2, s2) ACCUM(u3, s3)
        }
        for (; e < end; ++e) {
            int sv = csr[e];
            uint2 u = *(const uint2*)(fbf + (size_t)sv * D + off);
            ACCUM(u, s0)
        }
#undef ACCUM
        s0.x += s1.x + s2.x + s3.x;
        s0.y += s1.y + s2.y + s3.y;
        s0.z += s1.z + s2.z + s3.z;
        s0.w += s1.w + s2.w + s3.w;
        uint2 o;
        o.x = pk2(s0.x, s0.y);
        o.y = pk2(s0.z, s0.w);
        *(uint2*)(S + (size_t)v * D + off) = o;
    }
}

// ============================ MFMA dual GEMM (unchanged since R6) ==========
template <bool DEG, bool OUT_BF16>
__global__ __launch_bounds__(256, 2) void gemm_dual(
    const unsigned short* __restrict__ A1, const unsigned short* __restrict__ A2,
    const float* __restrict__ W1, const float* __restrict__ W2,
    const float* __restrict__ bias1, const float* __restrict__ bias2,
    const int* __restrict__ deg1, const int* __restrict__ deg2,
    void* outp, int M) {
    __shared__ unsigned int Wt[64 * 128];   // 64 n-rows x 256 k (bf16 pairs)
    __shared__ unsigned int At[128 * 64];   // 128 m-rows x 128 k (bf16 pairs)
    const int t  = threadIdx.x;
    const int r0 = blockIdx.x * 128;
    const int nb = blockIdx.y * 64;

#pragma unroll
    for (int i = 0; i < 8; ++i) {
        int g  = i * 256 + t;
        int j  = g >> 5;
        int cc = g & 31;
        int k  = cc * 8;
        const float* row = (k < 128) ? (W1 + (nb + j) * 128 + k)
                                     : (W2 + (nb + j) * 128 + (k - 128));
        float4 w0 = *(const float4*)(row);
        float4 w1 = *(const float4*)(row + 4);
        *(uint4*)(Wt + j * 128 + ((cc ^ (j & 7)) << 2)) =
            make_uint4(pk2(w0.x, w0.y), pk2(w0.z, w0.w), pk2(w1.x, w1.y), pk2(w1.z, w1.w));
    }
#define STAGE_A(AB)                                                             \
    {                                                                           \
        _Pragma("unroll") for (int i = 0; i < 8; ++i) {                         \
            int g  = i * 256 + t;                                               \
            int m  = g >> 4;                                                    \
            int cc = g & 15;                                                    \
            int r  = r0 + m;                                                    \
            uint4 v = make_uint4(0u, 0u, 0u, 0u);                               \
            if (r < M) v = *(const uint4*)((AB) + (size_t)r * 128 + cc * 8);    \
            *(uint4*)(At + m * 64 + ((cc ^ (m & 7)) << 2)) = v;                 \
        }                                                                       \
    }

    const int w    = t >> 6;
    const int w32  = w * 32;
    const int lane = t & 63;
    const int ln   = lane & 15;
    const int quad = lane >> 4;
    const int lnx  = ln & 7;
    const int rowA0 = (w32 + ln) * 64;
    const int rowA1 = (w32 + 16 + ln) * 64;
    const int rowB0 = (ln) * 128;
    const int rowB1 = (16 + ln) * 128;
    const int rowB2 = (32 + ln) * 128;
    const int rowB3 = (48 + ln) * 128;

    f32x4 acc00 = {0.f, 0.f, 0.f, 0.f}, acc01 = {0.f, 0.f, 0.f, 0.f};
    f32x4 acc02 = {0.f, 0.f, 0.f, 0.f}, acc03 = {0.f, 0.f, 0.f, 0.f};
    f32x4 acc10 = {0.f, 0.f, 0.f, 0.f}, acc11 = {0.f, 0.f, 0.f, 0.f};
    f32x4 acc12 = {0.f, 0.f, 0.f, 0.f}, acc13 = {0.f, 0.f, 0.f, 0.f};

#define KSTEP(KS, HC)                                                                \
    {                                                                                \
        const int ca = ((((KS)*4 + quad) ^ lnx) << 2);                               \
        bf16x8 a0 = *(const bf16x8*)(At + rowA0 + ca);                               \
        bf16x8 a1 = *(const bf16x8*)(At + rowA1 + ca);                               \
        const int cb = ((((HC) + (KS)*4 + quad) ^ lnx) << 2);                        \
        bf16x8 b0v = *(const bf16x8*)(Wt + rowB0 + cb);                              \
        bf16x8 b1v = *(const bf16x8*)(Wt + rowB1 + cb);                              \
        bf16x8 b2v = *(const bf16x8*)(Wt + rowB2 + cb);                              \
        bf16x8 b3v = *(const bf16x8*)(Wt + rowB3 + cb);                              \
        acc00 = __builtin_amdgcn_mfma_f32_16x16x32_bf16(a0, b0v, acc00, 0, 0, 0);    \
        acc01 = __builtin_amdgcn_mfma_f32_16x16x32_bf16(a0, b1v, acc01, 0, 0, 0);    \
        acc02 = __builtin_amdgcn_mfma_f32_16x16x32_bf16(a0, b2v, acc02, 0, 0, 0);    \
        acc03 = __builtin_amdgcn_mfma_f32_16x16x32_bf16(a0, b3v, acc03, 0, 0, 0);    \
        acc10 = __builtin_amdgcn_mfma_f32_16x16x32_bf16(a1, b0v, acc10, 0, 0, 0);    \
        acc11 = __builtin_amdgcn_mfma_f32_16x16x32_bf16(a1, b1v, acc11, 0, 0, 0);    \
        acc12 = __builtin_amdgcn_mfma_f32_16x16x32_bf16(a1, b2v, acc12, 0, 0, 0);    \
        acc13 = __builtin_amdgcn_mfma_f32_16x16x32_bf16(a1, b3v, acc13, 0, 0, 0);    \
    }

    STAGE_A(A1);
    __syncthreads();
    KSTEP(0, 0) KSTEP(1, 0) KSTEP(2, 0) KSTEP(3, 0)
    __syncthreads();
    STAGE_A(A2);
    __syncthreads();
    KSTEP(0, 16) KSTEP(1, 16) KSTEP(2, 16) KSTEP(3, 16)

#define EPI(ACC, MT, NI)                                                            \
    {                                                                               \
        const int col = nb + (NI)*16 + ln;                                          \
        float bc, be;                                                               \
        if (DEG) { bc = bias1[col]; be = bias2[col]; }                              \
        else     { bc = bias1[col] + bias2[col]; be = 0.f; }                        \
        _Pragma("unroll") for (int rg = 0; rg < 4; ++rg) {                          \
            const int rr = r0 + w32 + (MT)*16 + quad * 4 + rg;                      \
            if (rr < M) {                                                           \
                float val = ACC[rg];                                                \
                if (DEG) val += (float)deg1[rr] * bc + (float)deg2[rr] * be;        \
                else     val += bc;                                                 \
                if (OUT_BF16)                                                       \
                    ((unsigned short*)outp)[(size_t)rr * 128 + col] = f2bf(val);    \
                else                                                                \
                    ((float*)outp)[(size_t)rr * 128 + col] = val;                   \
            }                                                                       \
        }                                                                           \
    }
    EPI(acc00, 0, 0) EPI(acc01, 0, 1) EPI(acc02, 0, 2) EPI(acc03, 0, 3)
    EPI(acc10, 1, 0) EPI(acc11, 1, 1) EPI(acc12, 1, 2) EPI(acc13, 1, 3)
#undef EPI
#undef KSTEP
#undef STAGE_A
}

// ============================ driver =======================================
// 2N-segment CSR (elec dst offset +N), 8 launches. By linearity:
//   h   = S_c@Wc.T + S_e@We.T + deg_c*b_c + deg_e*b_e            [bf16, ws]
//   out = h@Wo.T + fbf@We.T + (b_o + b_e)                        [fp32, d_out]

extern "C" void kernel_launch(void* const* d_in, const int* in_sizes, int n_in,
                              void* d_out, int out_size, void* d_ws, size_t ws_size,
                              hipStream_t stream) {
    const float* feats  = (const float*)d_in[0];
    const float* W_chem = (const float*)d_in[1];
    const float* b_chem = (const float*)d_in[2];
    const float* W_elec = (const float*)d_in[3];
    const float* b_elec = (const float*)d_in[4];
    const float* W_out  = (const float*)d_in[5];
    const float* b_out  = (const float*)d_in[6];
    const int* src_chem = (const int*)d_in[7];
    const int* dst_chem = (const int*)d_in[8];
    const int* src_elec = (const int*)d_in[9];
    const int* dst_elec = (const int*)d_in[10];
    float* out = (float*)d_out;

    const int N = in_sizes[0] / D;  // 50000
    const int E = in_sizes[7];      // 500000
    const int N2 = 2 * N;

    // ws layout:
    unsigned short* fbf = (unsigned short*)d_ws;        // N*D bf16
    unsigned short* hbf = fbf + (size_t)N * D;          // N*D bf16
    int* c       = (int*)(hbf + (size_t)N * D);         // 2N (degrees; chem|elec)
    int* cursor  = c + N2;                              // 2N (absolute csr cursor)
    int* row_ptr = cursor + N2;                         // 2N+1 (+pad)
    int* aux     = row_ptr + N2 + 15;                   // 512
    unsigned short* csr = (unsigned short*)(aux + 512); // 2E u16

    // S_c|S_e live contiguously in d_out (bf16) until the final GEMM
    unsigned short* S = (unsigned short*)d_out;         // 2N rows

    const int nscan  = (N2 + 255) / 256;                // 391
    const int nagg   = (N2 + 31) / 32;
    const int n8     = N * D / 8;
    const int nedge4 = (2 * E + 1023) / 1024;           // 4 edges/thread
    dim3 gg((N + 127) / 128, 2);

    prep0<<<(n8 + 255) / 256, 256, 0, stream>>>((const float4*)feats, (uint4*)fbf,
                                                n8, c, N2);
    hist4<<<nedge4, 256, 0, stream>>>(dst_chem, dst_elec, c, E, N);
    scan_block<<<nscan, 256, 0, stream>>>(c, row_ptr, aux, N2);
    scan_add<<<nscan, 256, 0, stream>>>(row_ptr, aux, c, cursor, N2);
    fill4<<<nedge4, 256, 0, stream>>>(src_chem, dst_chem, src_elec, dst_elec,
                                      cursor, csr, E, N);
    aggregate_bf<<<nagg, 1024, 0, stream>>>(fbf, csr, row_ptr, S, N2);

    gemm_dual<true, true><<<gg, 256, 0, stream>>>(
        S, S + (size_t)N * D, W_chem, W_elec, b_chem, b_elec, c, c + N, hbf, N);
    gemm_dual<false, false><<<gg, 256, 0, stream>>>(
        hbf, fbf, W_out, W_elec, b_out, b_elec, nullptr, nullptr, out, N);
}